// Round 3
// baseline (4080.454 us; speedup 1.0000x reference)
//
#include <hip/hip_runtime.h>
#include <math.h>

#define BATCH 8
#define N 2048
#define D 256
#define K_INST 512
#define K_REL 32
#define PAIRS_PER_B (K_INST * K_REL)   // 16384

// ---------------------------------------------------------------------------
// Kernel 1: scores = q @ k^T  (per batch, 2048x2048x256, fp32)
// 128x128 tile, BK=16, 256 threads, 8x8 micro-tile split as 2x(4rows)x2x(4cols)
// at offsets {ty*4, 64+ty*4} x {tx*4, 64+tx*4} -> LDS b128 reads are 2-way
// aliased max (free). Double-buffered LDS, register prefetch, 1 barrier/iter.
// ---------------------------------------------------------------------------
#define BM 128
#define BN 128
#define BK 16
#define LDSS (BM + 4)

__global__ __launch_bounds__(256, 4)
void gemm_qkT(const float* __restrict__ q, const float* __restrict__ kmat,
              float* __restrict__ out) {
  const int bz = blockIdx.z;
  const int row0 = blockIdx.y * BM;
  const int col0 = blockIdx.x * BN;
  const float* Q = q + (size_t)bz * N * D;
  const float* Kp = kmat + (size_t)bz * N * D;
  float* O = out + (size_t)bz * N * N;

  __shared__ float Qs[2][BK][LDSS];
  __shared__ float Ks[2][BK][LDSS];

  const int tid = threadIdx.x;
  const int lr = tid >> 2;          // 0..63 (row slot)
  const int lc = (tid & 3) * 4;     // 0,4,8,12 (k-offset for staging float4)
  const int tx = tid & 15;
  const int ty = tid >> 4;

  const float* qp0 = Q + (size_t)(row0 + lr) * D + lc;
  const float* qp1 = Q + (size_t)(row0 + lr + 64) * D + lc;
  const float* kp0 = Kp + (size_t)(col0 + lr) * D + lc;
  const float* kp1 = Kp + (size_t)(col0 + lr + 64) * D + lc;

  float acc[8][8];
#pragma unroll
  for (int i = 0; i < 8; i++)
#pragma unroll
    for (int j = 0; j < 8; j++) acc[i][j] = 0.f;

  float4 a0 = *(const float4*)qp0;
  float4 a1 = *(const float4*)qp1;
  float4 b0 = *(const float4*)kp0;
  float4 b1 = *(const float4*)kp1;

  {
    float av0[4] = {a0.x, a0.y, a0.z, a0.w};
    float av1[4] = {a1.x, a1.y, a1.z, a1.w};
    float bv0[4] = {b0.x, b0.y, b0.z, b0.w};
    float bv1[4] = {b1.x, b1.y, b1.z, b1.w};
#pragma unroll
    for (int j = 0; j < 4; j++) {
      Qs[0][lc + j][lr] = av0[j];
      Qs[0][lc + j][lr + 64] = av1[j];
      Ks[0][lc + j][lr] = bv0[j];
      Ks[0][lc + j][lr + 64] = bv1[j];
    }
  }
  __syncthreads();

  const int ntiles = D / BK;  // 16
  for (int kt = 0; kt < ntiles; ++kt) {
    const int cur = kt & 1;
    if (kt + 1 < ntiles) {
      const int off = (kt + 1) * BK;
      a0 = *(const float4*)(qp0 + off);
      a1 = *(const float4*)(qp1 + off);
      b0 = *(const float4*)(kp0 + off);
      b1 = *(const float4*)(kp1 + off);
    }
#pragma unroll
    for (int kk = 0; kk < BK; ++kk) {
      const float4 qa = *(const float4*)&Qs[cur][kk][ty * 4];
      const float4 qb = *(const float4*)&Qs[cur][kk][64 + ty * 4];
      const float4 ka = *(const float4*)&Ks[cur][kk][tx * 4];
      const float4 kb = *(const float4*)&Ks[cur][kk][64 + tx * 4];
      float av[8] = {qa.x, qa.y, qa.z, qa.w, qb.x, qb.y, qb.z, qb.w};
      float bv[8] = {ka.x, ka.y, ka.z, ka.w, kb.x, kb.y, kb.z, kb.w};
#pragma unroll
      for (int i = 0; i < 8; i++)
#pragma unroll
        for (int j = 0; j < 8; j++)
          acc[i][j] = fmaf(av[i], bv[j], acc[i][j]);
    }
    if (kt + 1 < ntiles) {
      const int nxt = cur ^ 1;
      float av0[4] = {a0.x, a0.y, a0.z, a0.w};
      float av1[4] = {a1.x, a1.y, a1.z, a1.w};
      float bv0[4] = {b0.x, b0.y, b0.z, b0.w};
      float bv1[4] = {b1.x, b1.y, b1.z, b1.w};
#pragma unroll
      for (int j = 0; j < 4; j++) {
        Qs[nxt][lc + j][lr] = av0[j];
        Qs[nxt][lc + j][lr + 64] = av1[j];
        Ks[nxt][lc + j][lr] = bv0[j];
        Ks[nxt][lc + j][lr + 64] = bv1[j];
      }
      __syncthreads();
    }
  }

#pragma unroll
  for (int i = 0; i < 8; i++) {
    const int grow = row0 + ((i < 4) ? (ty * 4 + i) : (64 + ty * 4 + i - 4));
    float* orow = O + (size_t)grow * N + col0;
    *(float4*)(orow + tx * 4) = make_float4(acc[i][0], acc[i][1], acc[i][2], acc[i][3]);
    *(float4*)(orow + 64 + tx * 4) = make_float4(acc[i][4], acc[i][5], acc[i][6], acc[i][7]);
  }
}

// ---------------------------------------------------------------------------
// Kernel 2: per-row max, sum(exp), softmax diag. One WAVE per row, no barriers.
// Grid: B*N/4 blocks of 256 (4 waves = 4 rows).
// ---------------------------------------------------------------------------
__global__ __launch_bounds__(256)
void row_stats(const float* __restrict__ scores, float* __restrict__ m_out,
               float* __restrict__ s_out, float* __restrict__ diag_out) {
  const int wid = threadIdx.x >> 6;
  const int lane = threadIdx.x & 63;
  const int row = blockIdx.x * 4 + wid;
  const float* srow = scores + (size_t)row * N;
  const float4* r4 = (const float4*)srow;
  float4 v[8];
#pragma unroll
  for (int j = 0; j < 8; j++) v[j] = r4[lane + 64 * j];
  float mx = -3.4e38f;
#pragma unroll
  for (int j = 0; j < 8; j++)
    mx = fmaxf(mx, fmaxf(fmaxf(v[j].x, v[j].y), fmaxf(v[j].z, v[j].w)));
#pragma unroll
  for (int o = 1; o < 64; o <<= 1) mx = fmaxf(mx, __shfl_xor(mx, o));
  float s = 0.f;
#pragma unroll
  for (int j = 0; j < 8; j++)
    s += expf(v[j].x - mx) + expf(v[j].y - mx) + expf(v[j].z - mx) + expf(v[j].w - mx);
#pragma unroll
  for (int o = 1; o < 64; o <<= 1) s += __shfl_xor(s, o);
  if (lane == 0) {
    const int i = row & (N - 1);
    m_out[row] = mx;
    s_out[row] = s;
    diag_out[row] = expf(srow[i] - mx) / s;
  }
}

// ---------------------------------------------------------------------------
// Kernel 3: per-batch top-512 of diag (tie-break: lower index), indices
// emitted sorted ascending. 1024 threads, bitonic sort of 2048 in LDS.
// ---------------------------------------------------------------------------
__global__ __launch_bounds__(1024)
void topk_inst(const float* __restrict__ diag, int* __restrict__ inst) {
  const int b = blockIdx.x;
  __shared__ float v[2048];
  __shared__ int id[2048];
  __shared__ int sel[K_INST];
  const int tid = threadIdx.x;
  for (int e = tid; e < 2048; e += 1024) { v[e] = diag[b * N + e]; id[e] = e; }
  __syncthreads();
  for (int k = 2; k <= 2048; k <<= 1) {
    for (int j = k >> 1; j > 0; j >>= 1) {
      const int i = 2 * tid - (tid & (j - 1));
      const int ixj = i | j;
      const float va = v[i], vb = v[ixj];
      const int ia = id[i], ib = id[ixj];
      const bool a_first = (va > vb) || (va == vb && ia < ib);  // descending
      if (((i & k) == 0) != a_first) {
        v[i] = vb; v[ixj] = va; id[i] = ib; id[ixj] = ia;
      }
      __syncthreads();
    }
  }
  if (tid < K_INST) sel[tid] = id[tid];
  __syncthreads();
  for (int k = 2; k <= K_INST; k <<= 1) {
    for (int j = k >> 1; j > 0; j >>= 1) {
      if (tid < K_INST / 2) {
        const int i = 2 * tid - (tid & (j - 1));
        const int ixj = i | j;
        const int a = sel[i], c = sel[ixj];
        if (((i & k) == 0) != (a < c)) { sel[i] = c; sel[ixj] = a; }
      }
      __syncthreads();
    }
  }
  if (tid < K_INST) inst[b * K_INST + tid] = sel[tid];
}

// ---------------------------------------------------------------------------
// Kernel 4: rel row -> top-32 columns (tie-break lower col), cols sorted
// ascending; emit soi (floats) + int (subj,obj) pairs.
// One 256-thread block per rel row (4096 blocks), bitonic sort of 512.
// ---------------------------------------------------------------------------
__global__ __launch_bounds__(256)
void rel_topk(const float* __restrict__ scores, const float* __restrict__ m_arr,
              const float* __restrict__ s_arr, const int* __restrict__ inst,
              float* __restrict__ soi_out, int* __restrict__ pairs) {
  const int blk = blockIdx.x;
  const int b = blk >> 9;
  const int r = blk & 511;
  __shared__ float v[K_INST];
  __shared__ int c[K_INST];
  __shared__ int selc[K_REL];
  __shared__ int sortedc[K_REL];
  const int tid = threadIdx.x;
  const int subj = inst[b * K_INST + r];
  const int rowg = b * N + subj;
  const float m = m_arr[rowg];
  const float S = s_arr[rowg];
  const float* srow = scores + (size_t)rowg * N;
  for (int e = tid; e < K_INST; e += 256) {
    const int col = inst[b * K_INST + e];
    v[e] = (e == r) ? 1e9f : expf(srow[col] - m) / S;
    c[e] = e;
  }
  __syncthreads();
  for (int k = 2; k <= K_INST; k <<= 1) {
    for (int j = k >> 1; j > 0; j >>= 1) {
      const int i = 2 * tid - (tid & (j - 1));
      const int ixj = i | j;
      const float va = v[i], vb = v[ixj];
      const int ia = c[i], ib = c[ixj];
      const bool a_first = (va > vb) || (va == vb && ia < ib);
      if (((i & k) == 0) != a_first) {
        v[i] = vb; v[ixj] = va; c[i] = ib; c[ixj] = ia;
      }
      __syncthreads();
    }
  }
  if (tid < K_REL) selc[tid] = c[tid];
  __syncthreads();
  if (tid < K_REL) {
    const int myc = selc[tid];
    int rank = 0;
#pragma unroll
    for (int p2 = 0; p2 < K_REL; p2++) rank += (selc[p2] < myc);
    sortedc[rank] = myc;
  }
  __syncthreads();
  if (tid < K_REL) {
    const int cc = sortedc[tid];
    const int obj = inst[b * K_INST + cc];
    const size_t pidx = (size_t)b * PAIRS_PER_B + (size_t)r * K_REL + tid;
    soi_out[pidx * 3 + 0] = (float)b;
    soi_out[pidx * 3 + 1] = (float)subj;
    soi_out[pidx * 3 + 2] = (float)obj;
    pairs[pidx * 2 + 0] = subj;
    pairs[pidx * 2 + 1] = obj;
  }
}

// ---------------------------------------------------------------------------
// Kernel 5: rel_e = layernorm(q[subj]+q[obj]) over D=256. One WAVE per pair,
// 4 floats/lane, shuffle-only reductions, no LDS/barriers.
// ---------------------------------------------------------------------------
__global__ __launch_bounds__(256)
void rel_embed(const float* __restrict__ q, const int* __restrict__ pairs,
               float* __restrict__ out) {
  const int wid = threadIdx.x >> 6;
  const int lane = threadIdx.x & 63;
  const size_t p = (size_t)blockIdx.x * 4 + wid;
  const int b = (int)(p >> 14);
  const int subj = pairs[p * 2], obj = pairs[p * 2 + 1];
  const float4* qs = (const float4*)(q + ((size_t)b * N + subj) * D);
  const float4* qo = (const float4*)(q + ((size_t)b * N + obj) * D);
  const float4 s4 = qs[lane];
  const float4 o4 = qo[lane];
  float ex = s4.x + o4.x, ey = s4.y + o4.y, ez = s4.z + o4.z, ew = s4.w + o4.w;
  float s = ex + ey + ez + ew;
#pragma unroll
  for (int o = 1; o < 64; o <<= 1) s += __shfl_xor(s, o);
  const float mu = s * (1.0f / D);
  const float dx = ex - mu, dy = ey - mu, dz = ez - mu, dw = ew - mu;
  float s2 = dx * dx + dy * dy + dz * dz + dw * dw;
#pragma unroll
  for (int o = 1; o < 64; o <<= 1) s2 += __shfl_xor(s2, o);
  const float r = rsqrtf(s2 * (1.0f / D) + 1e-5f);
  ((float4*)(out + p * D))[lane] = make_float4(dx * r, dy * r, dz * r, dw * r);
}

// ---------------------------------------------------------------------------
extern "C" void kernel_launch(void* const* d_in, const int* in_sizes, int n_in,
                              void* d_out, int out_size, void* d_ws, size_t ws_size,
                              hipStream_t stream) {
  const float* q = (const float*)d_in[0];
  const float* k = (const float*)d_in[1];
  float* out = (float*)d_out;

  float* scores = out;                                   // 8*2048*2048
  float* soi = out + (size_t)BATCH * N * N;              // 8*16384*3
  float* rele = soi + (size_t)BATCH * PAIRS_PER_B * 3;   // 8*16384*256

  float* m_arr = (float*)d_ws;                 // 16384 f
  float* s_arr = m_arr + BATCH * N;            // 16384 f
  float* diag = s_arr + BATCH * N;             // 16384 f
  int* inst = (int*)(diag + BATCH * N);        // 4096 i
  int* pairs = inst + BATCH * K_INST;          // 262144 i

  gemm_qkT<<<dim3(N / BN, N / BM, BATCH), 256, 0, stream>>>(q, k, scores);
  row_stats<<<BATCH * N / 4, 256, 0, stream>>>(scores, m_arr, s_arr, diag);
  topk_inst<<<BATCH, 1024, 0, stream>>>(diag, inst);
  rel_topk<<<BATCH * K_INST, 256, 0, stream>>>(scores, m_arr, s_arr, inst, soi, pairs);
  rel_embed<<<BATCH * PAIRS_PER_B / 4, 256, 0, stream>>>(q, pairs, rele);
}